// Round 7
// baseline (569.633 us; speedup 1.0000x reference)
//
#include <hip/hip_runtime.h>
#include <stdint.h>

// Pipeline: cast->bf16 | rope table | QKV GEMM (bf16 MFMA) | rope+layout |
//           V-transpose | flash attention (barrier-free, global-direct K/V) |
//           out-proj GEMM
// B=2 T=2048 D_MODEL=2048 H=32 KVH=8 HD=64

typedef unsigned short u16;
typedef __attribute__((ext_vector_type(8))) short short8;
typedef __attribute__((ext_vector_type(4))) float floatx4;

#define T_SEQ 2048
#define DMODEL 2048
#define NHEADS 32
#define KVHEADS 8
#define HDIM 64
// 0.125 (1/sqrt(64)) * log2(e): QK^T then exp2 == exp(0.125*qk)
#define QK_SCALE 0.1803368801111204f

__device__ __forceinline__ u16 f2bf(float f) {
  uint32_t u = __builtin_bit_cast(uint32_t, f);
  u = (u + 0x7FFFu + ((u >> 16) & 1u)) >> 16;
  return (u16)u;
}
__device__ __forceinline__ float bf2f(u16 h) {
  uint32_t u = ((uint32_t)h) << 16;
  return __builtin_bit_cast(float, u);
}

__device__ __forceinline__ void gld_lds16(const void* g, void* l) {
  __builtin_amdgcn_global_load_lds(
      (const __attribute__((address_space(1))) unsigned int*)g,
      (__attribute__((address_space(3))) unsigned int*)l, 16, 0, 0);
}

// ---------------- f32 -> bf16 cast (x4 vectorized) ----------------
__global__ __launch_bounds__(256) void cvt_kernel(const float* __restrict__ src,
                                                  u16* __restrict__ dst, int n4) {
  int i = blockIdx.x * 256 + threadIdx.x;
  if (i >= n4) return;
  float4 v = ((const float4*)src)[i];
  ushort4 o;
  o.x = f2bf(v.x); o.y = f2bf(v.y); o.z = f2bf(v.z); o.w = f2bf(v.w);
  ((ushort4*)dst)[i] = o;
}

// ---------------- rope table: cos/sin [T][32] ----------------
__global__ __launch_bounds__(256) void rope_table_kernel(float* __restrict__ cosT,
                                                         float* __restrict__ sinT) {
  int idx = blockIdx.x * 256 + threadIdx.x;  // 65536 = 2048*32
  int t = idx >> 5, i = idx & 31;
  float invf = 1.0f / powf(10000.0f, (float)i / 32.0f);
  float a = (float)t * invf;
  cosT[idx] = cosf(a);
  sinT[idx] = sinf(a);
}

// ---------------- bf16 GEMM, A[M,K] * B[N,K]^T -> C[M,N] ----------------
template <bool OUT_F32>
__global__ __launch_bounds__(256) void gemm_bt(const u16* __restrict__ A,
                                               const u16* __restrict__ Bm,
                                               float* __restrict__ Cf,
                                               u16* __restrict__ Cb,
                                               int M, int N, int K) {
  __shared__ u16 As[128 * 64];
  __shared__ u16 Bs[128 * 64];
  const int tid = threadIdx.x;
  const int lane = tid & 63;
  const int wid = tid >> 6;
  const int wr = wid >> 1, wc = wid & 1;
  const long bm = (long)blockIdx.y * 128;
  const long bn = (long)blockIdx.x * 128;

  floatx4 acc[4][4] = {};

  for (int kt = 0; kt < K; kt += 64) {
#pragma unroll
    for (int c = 0; c < 4; ++c) {
      int g = (wid * 4 + c) * 64 + lane;      // 16B granule index, 1024 total
      int row = g >> 3, slot = g & 7;
      int ss = slot ^ (row & 7);              // inverse-swizzle the SOURCE
      gld_lds16(A + (bm + row) * (long)K + kt + ss * 8, (char*)As + g * 16);
      gld_lds16(Bm + (bn + row) * (long)K + kt + ss * 8, (char*)Bs + g * 16);
    }
    __syncthreads();
#pragma unroll
    for (int ks = 0; ks < 2; ++ks) {
      short8 af[4], bfr[4];
#pragma unroll
      for (int m = 0; m < 4; ++m) {
        int row = wr * 64 + m * 16 + (lane & 15);
        int slot = (ks * 4 + (lane >> 4)) ^ (row & 7);
        af[m] = *(const short8*)((const char*)As + row * 128 + slot * 16);
      }
#pragma unroll
      for (int n = 0; n < 4; ++n) {
        int row = wc * 64 + n * 16 + (lane & 15);
        int slot = (ks * 4 + (lane >> 4)) ^ (row & 7);
        bfr[n] = *(const short8*)((const char*)Bs + row * 128 + slot * 16);
      }
#pragma unroll
      for (int m = 0; m < 4; ++m)
#pragma unroll
        for (int n = 0; n < 4; ++n)
          acc[m][n] = __builtin_amdgcn_mfma_f32_16x16x32_bf16(af[m], bfr[n],
                                                              acc[m][n], 0, 0, 0);
    }
    __syncthreads();
  }
#pragma unroll
  for (int m = 0; m < 4; ++m)
#pragma unroll
    for (int n = 0; n < 4; ++n)
#pragma unroll
      for (int r = 0; r < 4; ++r) {
        long row = bm + wr * 64 + m * 16 + (lane >> 4) * 4 + r;
        long col = bn + wc * 64 + n * 16 + (lane & 15);
        if constexpr (OUT_F32)
          Cf[row * N + col] = acc[m][n][r];
        else
          Cb[row * N + col] = f2bf(acc[m][n][r]);
      }
}

// ---------------- RoPE + head layout for Q,K ----------------
// Q additionally pre-scaled by 0.125*log2(e) so attn softmax runs in exp2.
__global__ __launch_bounds__(256) void rope_apply_kernel(
    const u16* __restrict__ QKV, const float* __restrict__ cosT,
    const float* __restrict__ sinT, u16* __restrict__ Qh, u16* __restrict__ Kh) {
  int idx = blockIdx.x * 256 + threadIdx.x;  // B*T*2560
  int c = idx % 2560;
  int bt = idx / 2560;
  int t = bt & (T_SEQ - 1);
  int b = bt >> 11;
  int hd = c & 63;
  int i = hd & 31;
  float cs = cosT[t * 32 + i];
  float sn = sinT[t * 32 + i];
  long base = (long)bt * 3072;
  float xv = bf2f(QKV[base + c]);
  int pairc = (hd < 32) ? c + 32 : c - 32;
  float xp = bf2f(QKV[base + pairc]);
  float rot = (hd < 32) ? -xp : xp;
  float ov = xv * cs + rot * sn;
  if (c < 2048) {
    int h = c >> 6;
    Qh[((long)(b * NHEADS + h) * T_SEQ + t) * HDIM + hd] = f2bf(ov * QK_SCALE);
  } else {
    int kv = (c - 2048) >> 6;
    Kh[((long)(b * KVHEADS + kv) * T_SEQ + t) * HDIM + hd] = f2bf(ov);
  }
}

// ---------------- V transpose: QKV V-cols -> Vt[B][KVH][D][T] ----------------
__global__ __launch_bounds__(256) void v_transpose_kernel(const u16* __restrict__ QKV,
                                                          u16* __restrict__ Vt) {
  __shared__ u16 tl[64 * 65];
  int blk = blockIdx.x;  // 512 = B*KVH*(T/64)
  int ttile = blk & 31;
  int kvh = (blk >> 5) & 7;
  int b = blk >> 8;
  int tid = threadIdx.x;
  long bt0 = (long)b * T_SEQ + ttile * 64;
#pragma unroll
  for (int j = 0; j < 2; ++j) {
    int chunk = tid * 2 + j;
    int el = chunk * 8;
    int row = el >> 6, col = el & 63;
    short8 v = *(const short8*)(QKV + (bt0 + row) * 3072 + 2560 + kvh * 64 + col);
#pragma unroll
    for (int k = 0; k < 8; ++k) tl[(col + k) * 65 + row] = (u16)v[k];
  }
  __syncthreads();
#pragma unroll
  for (int j = 0; j < 2; ++j) {
    int chunk = tid * 2 + j;
    int el = chunk * 8;
    int d = el >> 6, t0 = el & 63;
    short8 o;
#pragma unroll
    for (int k = 0; k < 8; ++k) o[k] = (short)tl[d * 65 + t0 + k];
    *(short8*)(Vt + ((long)(b * KVHEADS + kvh) * HDIM + d) * T_SEQ + ttile * 64 + t0) = o;
  }
}

// ---------------- causal GQA flash attention (barrier-free) ----------------
// K/V fragments loaded DIRECTLY from global as short8 (L1/L2 serve the 4-wave
// reuse; no LDS staging, no barriers, waves fully independent). LDS only for
// the per-wave P round-trip. Softmax in exp2 domain (scale folded into Q).
// XCD-chunked block swizzle: each XCD sees 8 consecutive heads -> 1MB KV in L2.
__global__ __launch_bounds__(256, 4) void attn_kernel(const u16* __restrict__ Qh,
                                                      const u16* __restrict__ Kh,
                                                      const u16* __restrict__ Vt,
                                                      u16* __restrict__ O) {
  __shared__ u16 Ps[4 * 1024];  // per-wave P tile [16 q][64 t]
  const int tid = threadIdx.x;
  const int lane = tid & 63;
  const int w = tid >> 6;
  const int blk0 = blockIdx.x;
  const int swz = (blk0 & 7) * 256 + (blk0 >> 3);  // XCD-chunked (2048 % 8 == 0)
  const int qb = 31 - (swz & 31);  // heavy blocks first within each XCD stream
  const int h = (swz >> 5) & 31;
  const int b = swz >> 10;
  const int kvh = h >> 2;
  const int qbase = qb * 64;
  const int l15 = lane & 15;
  const int l4 = lane >> 4;

  const u16* Qp = Qh + ((long)(b * NHEADS + h) * T_SEQ + qbase + w * 16 + l15) * HDIM;
  short8 qf0 = *(const short8*)(Qp + l4 * 8);
  short8 qf1 = *(const short8*)(Qp + 32 + l4 * 8);
  const u16* Kbase = Kh + (long)(b * KVHEADS + kvh) * T_SEQ * HDIM;
  const u16* Vbase = Vt + (long)(b * KVHEADS + kvh) * HDIM * T_SEQ;

  float m_run = -1e30f, l_run = 0.f;
  floatx4 oA[4] = {};
  const int qg = qbase + w * 16 + l15;  // this lane's q row (stats owner)
  char* Pw = (char*)Ps + w * 2048;

  for (int kt = 0; kt <= qb; ++kt) {
    const u16* Kt = Kbase + (long)kt * 64 * HDIM;
    const u16* Vti = Vbase + kt * 64;

    // S^T[t][q] = sum_d K[t][d] Q[q][d]; K-frags straight from global
    floatx4 st[4] = {};
    __builtin_amdgcn_s_setprio(1);
#pragma unroll
    for (int ks = 0; ks < 2; ++ks) {
      short8 qf = ks ? qf1 : qf0;
#pragma unroll
      for (int tt = 0; tt < 4; ++tt) {
        short8 kf = *(const short8*)(Kt + (tt * 16 + l15) * HDIM + ks * 32 + l4 * 8);
        st[tt] = __builtin_amdgcn_mfma_f32_16x16x32_bf16(kf, qf, st[tt], 0, 0, 0);
      }
    }
    __builtin_amdgcn_s_setprio(0);

    // causal mask on the diagonal tile only (scale pre-folded into Q)
    if (kt == qb) {
#pragma unroll
      for (int tt = 0; tt < 4; ++tt)
#pragma unroll
        for (int r = 0; r < 4; ++r) {
          int tg = kt * 64 + tt * 16 + l4 * 4 + r;
          if (tg > qg) st[tt][r] = -1e30f;
        }
    }
    // tile max (tree) + wave reduce over the 4 lanes sharing q
    float mx0 = fmaxf(fmaxf(st[0][0], st[0][1]), fmaxf(st[0][2], st[0][3]));
    float mx1 = fmaxf(fmaxf(st[1][0], st[1][1]), fmaxf(st[1][2], st[1][3]));
    float mx2 = fmaxf(fmaxf(st[2][0], st[2][1]), fmaxf(st[2][2], st[2][3]));
    float mx3 = fmaxf(fmaxf(st[3][0], st[3][1]), fmaxf(st[3][2], st[3][3]));
    float mt = fmaxf(fmaxf(mx0, mx1), fmaxf(mx2, mx3));
    mt = fmaxf(mt, __shfl_xor(mt, 16));
    mt = fmaxf(mt, __shfl_xor(mt, 32));

    // T13 defer-max (log2 units; P bounded by 2^8)
    bool defer = __all(mt - m_run <= 8.0f);
    float m_use = defer ? m_run : fmaxf(m_run, mt);
    float alpha = defer ? 1.0f : exp2f(m_run - m_use);

    // exp2 in place + per-tt partial sums
    float lsp[4];
#pragma unroll
    for (int tt = 0; tt < 4; ++tt) {
      float e0 = exp2f(st[tt][0] - m_use);
      float e1 = exp2f(st[tt][1] - m_use);
      float e2 = exp2f(st[tt][2] - m_use);
      float e3 = exp2f(st[tt][3] - m_use);
      st[tt][0] = e0; st[tt][1] = e1; st[tt][2] = e2; st[tt][3] = e3;
      lsp[tt] = (e0 + e1) + (e2 + e3);
    }
    float lsum = (lsp[0] + lsp[1]) + (lsp[2] + lsp[3]);
    lsum += __shfl_xor(lsum, 16);
    lsum += __shfl_xor(lsum, 32);
    l_run = l_run * alpha + lsum;
    m_run = m_use;

    // P (bf16) -> per-wave LDS, swizzled rows of 128B
#pragma unroll
    for (int tt = 0; tt < 4; ++tt) {
      uint2 pk;
      pk.x = (uint32_t)f2bf(st[tt][0]) | ((uint32_t)f2bf(st[tt][1]) << 16);
      pk.y = (uint32_t)f2bf(st[tt][2]) | ((uint32_t)f2bf(st[tt][3]) << 16);
      int t0 = tt * 16 + l4 * 4;
      int slot = (t0 >> 3) ^ (l15 & 7);
      int half = (t0 & 4) ? 8 : 0;
      *(uint2*)(Pw + l15 * 128 + slot * 16 + half) = pk;
    }
    asm volatile("s_waitcnt lgkmcnt(0)" ::: "memory");

    // O rescale only when max advanced
    if (!defer) {
      float a0 = __shfl(alpha, l4 * 4 + 0);
      float a1 = __shfl(alpha, l4 * 4 + 1);
      float a2 = __shfl(alpha, l4 * 4 + 2);
      float a3 = __shfl(alpha, l4 * 4 + 3);
#pragma unroll
      for (int dd = 0; dd < 4; ++dd) {
        oA[dd][0] *= a0; oA[dd][1] *= a1; oA[dd][2] *= a2; oA[dd][3] *= a3;
      }
    }

    // O[q][d] += P[q][t] V[t][d]; V-frags straight from global (Vt is [d][t])
    __builtin_amdgcn_s_setprio(1);
#pragma unroll
    for (int ks2 = 0; ks2 < 2; ++ks2) {
      int slotp = (ks2 * 4 + l4) ^ (l15 & 7);
      short8 pa = *(const short8*)(Pw + l15 * 128 + slotp * 16);
#pragma unroll
      for (int dd = 0; dd < 4; ++dd) {
        short8 vb = *(const short8*)(Vti + (dd * 16 + l15) * (long)T_SEQ + ks2 * 32 + l4 * 8);
        oA[dd] = __builtin_amdgcn_mfma_f32_16x16x32_bf16(pa, vb, oA[dd], 0, 0, 0);
      }
    }
    __builtin_amdgcn_s_setprio(0);
  }

  float linv = 1.0f / l_run;
  float i0 = __shfl(linv, l4 * 4 + 0);
  float i1 = __shfl(linv, l4 * 4 + 1);
  float i2 = __shfl(linv, l4 * 4 + 2);
  float i3 = __shfl(linv, l4 * 4 + 3);
  float iv[4] = {i0, i1, i2, i3};
#pragma unroll
  for (int dd = 0; dd < 4; ++dd)
#pragma unroll
    for (int r = 0; r < 4; ++r) {
      int trow = qbase + w * 16 + l4 * 4 + r;
      int col = h * 64 + dd * 16 + l15;
      O[((long)b * T_SEQ + trow) * DMODEL + col] = f2bf(oA[dd][r] * iv[r]);
    }
}

extern "C" void kernel_launch(void* const* d_in, const int* in_sizes, int n_in,
                              void* d_out, int out_size, void* d_ws, size_t ws_size,
                              hipStream_t stream) {
  const float* x = (const float*)d_in[0];
  const float* Wq = (const float*)d_in[1];
  const float* Wk = (const float*)d_in[2];
  const float* Wv = (const float*)d_in[3];
  const float* Wo = (const float*)d_in[4];
  float* out = (float*)d_out;

  // ws layout (bytes); Obuf aliases x_bf (dead after GEMM1). Total 88,604,672 B.
  char* ws = (char*)d_ws;
  u16* x_bf = (u16*)(ws);                    // 16,777,216
  u16* Obuf = (u16*)(ws);                    // alias
  u16* Wqkv_bf = (u16*)(ws + 16777216);      // 12,582,912
  u16* Wo_bf = (u16*)(ws + 29360128);        //  8,388,608
  u16* QKV = (u16*)(ws + 37748736);          // 25,165,824
  u16* Qh = (u16*)(ws + 62914560);           // 16,777,216
  u16* Kh = (u16*)(ws + 79691776);           //  4,194,304
  u16* Vt = (u16*)(ws + 83886080);           //  4,194,304
  float* cosT = (float*)(ws + 88080384);     //    262,144
  float* sinT = (float*)(ws + 88342528);     //    262,144

  // casts
  cvt_kernel<<<8192, 256, 0, stream>>>(x, x_bf, 2097152);
  cvt_kernel<<<4096, 256, 0, stream>>>(Wq, Wqkv_bf, 1048576);
  cvt_kernel<<<1024, 256, 0, stream>>>(Wk, Wqkv_bf + 2048 * 2048, 262144);
  cvt_kernel<<<1024, 256, 0, stream>>>(Wv, Wqkv_bf + 2560 * 2048, 262144);
  cvt_kernel<<<4096, 256, 0, stream>>>(Wo, Wo_bf, 1048576);
  rope_table_kernel<<<256, 256, 0, stream>>>(cosT, sinT);

  // QKV projection: [4096,2048] x [3072,2048]^T -> [4096,3072] bf16
  dim3 g1(24, 32);
  gemm_bt<false><<<g1, 256, 0, stream>>>(x_bf, Wqkv_bf, nullptr, QKV, 4096, 3072, 2048);

  rope_apply_kernel<<<40960, 256, 0, stream>>>(QKV, cosT, sinT, Qh, Kh);
  v_transpose_kernel<<<512, 256, 0, stream>>>(QKV, Vt);

  attn_kernel<<<2048, 256, 0, stream>>>(Qh, Kh, Vt, Obuf);

  // out projection: [4096,2048] x [2048,2048]^T -> f32 d_out
  dim3 g2(16, 32);
  gemm_bt<true><<<g2, 256, 0, stream>>>(Obuf, Wo_bf, out, nullptr, 4096, 2048, 2048);
}

// Round 8
// 371.599 us; speedup vs baseline: 1.5329x; 1.5329x over previous
//
#include <hip/hip_runtime.h>
#include <stdint.h>

// Pipeline: cast->bf16 | rope table | QKV GEMM (bf16 MFMA) | rope+layout |
//           V-transpose | flash attention (staged dbuf, VALU-diet) | out-proj
// B=2 T=2048 D_MODEL=2048 H=32 KVH=8 HD=64

typedef unsigned short u16;
typedef __attribute__((ext_vector_type(8))) short short8;
typedef __attribute__((ext_vector_type(4))) float floatx4;

#define T_SEQ 2048
#define DMODEL 2048
#define NHEADS 32
#define KVHEADS 8
#define HDIM 64
// 0.125 (1/sqrt(64)) * log2(e): QK^T then exp2 == exp(0.125*qk)
#define QK_SCALE 0.1803368801111204f

__device__ __forceinline__ u16 f2bf(float f) {
  uint32_t u = __builtin_bit_cast(uint32_t, f);
  u = (u + 0x7FFFu + ((u >> 16) & 1u)) >> 16;
  return (u16)u;
}
__device__ __forceinline__ float bf2f(u16 h) {
  uint32_t u = ((uint32_t)h) << 16;
  return __builtin_bit_cast(float, u);
}
__device__ __forceinline__ uint32_t cvtpk(float a, float b) {  // lo=a, hi=b
  uint32_t r;
  asm("v_cvt_pk_bf16_f32 %0, %1, %2" : "=v"(r) : "v"(a), "v"(b));
  return r;
}

__device__ __forceinline__ void gld_lds16(const void* g, void* l) {
  __builtin_amdgcn_global_load_lds(
      (const __attribute__((address_space(1))) unsigned int*)g,
      (__attribute__((address_space(3))) unsigned int*)l, 16, 0, 0);
}

// ---------------- f32 -> bf16 cast (x4 vectorized) ----------------
__global__ __launch_bounds__(256) void cvt_kernel(const float* __restrict__ src,
                                                  u16* __restrict__ dst, int n4) {
  int i = blockIdx.x * 256 + threadIdx.x;
  if (i >= n4) return;
  float4 v = ((const float4*)src)[i];
  ushort4 o;
  o.x = f2bf(v.x); o.y = f2bf(v.y); o.z = f2bf(v.z); o.w = f2bf(v.w);
  ((ushort4*)dst)[i] = o;
}

// ---------------- rope table: cos/sin [T][32] ----------------
__global__ __launch_bounds__(256) void rope_table_kernel(float* __restrict__ cosT,
                                                         float* __restrict__ sinT) {
  int idx = blockIdx.x * 256 + threadIdx.x;  // 65536 = 2048*32
  int t = idx >> 5, i = idx & 31;
  float invf = 1.0f / powf(10000.0f, (float)i / 32.0f);
  float a = (float)t * invf;
  cosT[idx] = cosf(a);
  sinT[idx] = sinf(a);
}

// ---------------- bf16 GEMM, A[M,K] * B[N,K]^T -> C[M,N] ----------------
template <bool OUT_F32>
__global__ __launch_bounds__(256) void gemm_bt(const u16* __restrict__ A,
                                               const u16* __restrict__ Bm,
                                               float* __restrict__ Cf,
                                               u16* __restrict__ Cb,
                                               int M, int N, int K) {
  __shared__ u16 As[128 * 64];
  __shared__ u16 Bs[128 * 64];
  const int tid = threadIdx.x;
  const int lane = tid & 63;
  const int wid = tid >> 6;
  const int wr = wid >> 1, wc = wid & 1;
  const long bm = (long)blockIdx.y * 128;
  const long bn = (long)blockIdx.x * 128;

  floatx4 acc[4][4] = {};

  for (int kt = 0; kt < K; kt += 64) {
#pragma unroll
    for (int c = 0; c < 4; ++c) {
      int g = (wid * 4 + c) * 64 + lane;      // 16B granule index, 1024 total
      int row = g >> 3, slot = g & 7;
      int ss = slot ^ (row & 7);              // inverse-swizzle the SOURCE
      gld_lds16(A + (bm + row) * (long)K + kt + ss * 8, (char*)As + g * 16);
      gld_lds16(Bm + (bn + row) * (long)K + kt + ss * 8, (char*)Bs + g * 16);
    }
    __syncthreads();
#pragma unroll
    for (int ks = 0; ks < 2; ++ks) {
      short8 af[4], bfr[4];
#pragma unroll
      for (int m = 0; m < 4; ++m) {
        int row = wr * 64 + m * 16 + (lane & 15);
        int slot = (ks * 4 + (lane >> 4)) ^ (row & 7);
        af[m] = *(const short8*)((const char*)As + row * 128 + slot * 16);
      }
#pragma unroll
      for (int n = 0; n < 4; ++n) {
        int row = wc * 64 + n * 16 + (lane & 15);
        int slot = (ks * 4 + (lane >> 4)) ^ (row & 7);
        bfr[n] = *(const short8*)((const char*)Bs + row * 128 + slot * 16);
      }
#pragma unroll
      for (int m = 0; m < 4; ++m)
#pragma unroll
        for (int n = 0; n < 4; ++n)
          acc[m][n] = __builtin_amdgcn_mfma_f32_16x16x32_bf16(af[m], bfr[n],
                                                              acc[m][n], 0, 0, 0);
    }
    __syncthreads();
  }
#pragma unroll
  for (int m = 0; m < 4; ++m)
#pragma unroll
    for (int n = 0; n < 4; ++n)
#pragma unroll
      for (int r = 0; r < 4; ++r) {
        long row = bm + wr * 64 + m * 16 + (lane >> 4) * 4 + r;
        long col = bn + wc * 64 + n * 16 + (lane & 15);
        if constexpr (OUT_F32)
          Cf[row * N + col] = acc[m][n][r];
        else
          Cb[row * N + col] = f2bf(acc[m][n][r]);
      }
}

// ---------------- RoPE + head layout for Q,K ----------------
// Q additionally pre-scaled by 0.125*log2(e) so attn softmax runs in exp2.
__global__ __launch_bounds__(256) void rope_apply_kernel(
    const u16* __restrict__ QKV, const float* __restrict__ cosT,
    const float* __restrict__ sinT, u16* __restrict__ Qh, u16* __restrict__ Kh) {
  int idx = blockIdx.x * 256 + threadIdx.x;  // B*T*2560
  int c = idx % 2560;
  int bt = idx / 2560;
  int t = bt & (T_SEQ - 1);
  int b = bt >> 11;
  int hd = c & 63;
  int i = hd & 31;
  float cs = cosT[t * 32 + i];
  float sn = sinT[t * 32 + i];
  long base = (long)bt * 3072;
  float xv = bf2f(QKV[base + c]);
  int pairc = (hd < 32) ? c + 32 : c - 32;
  float xp = bf2f(QKV[base + pairc]);
  float rot = (hd < 32) ? -xp : xp;
  float ov = xv * cs + rot * sn;
  if (c < 2048) {
    int h = c >> 6;
    Qh[((long)(b * NHEADS + h) * T_SEQ + t) * HDIM + hd] = f2bf(ov * QK_SCALE);
  } else {
    int kv = (c - 2048) >> 6;
    Kh[((long)(b * KVHEADS + kv) * T_SEQ + t) * HDIM + hd] = f2bf(ov);
  }
}

// ---------------- V transpose: QKV V-cols -> Vt[B][KVH][D][T] ----------------
__global__ __launch_bounds__(256) void v_transpose_kernel(const u16* __restrict__ QKV,
                                                          u16* __restrict__ Vt) {
  __shared__ u16 tl[64 * 65];
  int blk = blockIdx.x;  // 512 = B*KVH*(T/64)
  int ttile = blk & 31;
  int kvh = (blk >> 5) & 7;
  int b = blk >> 8;
  int tid = threadIdx.x;
  long bt0 = (long)b * T_SEQ + ttile * 64;
#pragma unroll
  for (int j = 0; j < 2; ++j) {
    int chunk = tid * 2 + j;
    int el = chunk * 8;
    int row = el >> 6, col = el & 63;
    short8 v = *(const short8*)(QKV + (bt0 + row) * 3072 + 2560 + kvh * 64 + col);
#pragma unroll
    for (int k = 0; k < 8; ++k) tl[(col + k) * 65 + row] = (u16)v[k];
  }
  __syncthreads();
#pragma unroll
  for (int j = 0; j < 2; ++j) {
    int chunk = tid * 2 + j;
    int el = chunk * 8;
    int d = el >> 6, t0 = el & 63;
    short8 o;
#pragma unroll
    for (int k = 0; k < 8; ++k) o[k] = (short)tl[d * 65 + t0 + k];
    *(short8*)(Vt + ((long)(b * KVHEADS + kvh) * HDIM + d) * T_SEQ + ttile * 64 + t0) = o;
  }
}

// ---------------- causal GQA flash attention ----------------
// Staged dbuf (R6 structure) + VALU diet: all LDS addrs = 2 precomputed lane
// bases + compile-time offsets (manual 2x unroll, BUF constexpr); cvt_pk for
// P-pack; vmcnt+barrier at iter TOP (full-iteration load window); exp2 domain.
#define ATT_BODY(BUF)                                                          \
  {                                                                            \
    asm volatile("s_waitcnt vmcnt(0)" ::: "memory");                           \
    __builtin_amdgcn_s_barrier();                                              \
    asm volatile("" ::: "memory");                                             \
    if (kt < qb) {                                                             \
      gld_lds16(kg0, (char*)KS + ((BUF ^ 1) * 8192) + ld0);                    \
      gld_lds16(kg1, (char*)KS + ((BUF ^ 1) * 8192) + ld1);                    \
      gld_lds16(vg0, (char*)VS + ((BUF ^ 1) * 8192) + ld0);                    \
      gld_lds16(vg1, (char*)VS + ((BUF ^ 1) * 8192) + ld1);                    \
      kg0 += 4096; kg1 += 4096; vg0 += 64; vg1 += 64;                          \
    }                                                                          \
    floatx4 st[4] = {};                                                        \
    __builtin_amdgcn_s_setprio(1);                                             \
    {                                                                          \
      short8 kf0 = *(const short8*)((const char*)KS + BUF * 8192 + aK0);       \
      short8 kf1 = *(const short8*)((const char*)KS + BUF * 8192 + aK0 + 2048);\
      short8 kf2 = *(const short8*)((const char*)KS + BUF * 8192 + aK0 + 4096);\
      short8 kf3 = *(const short8*)((const char*)KS + BUF * 8192 + aK0 + 6144);\
      st[0] = __builtin_amdgcn_mfma_f32_16x16x32_bf16(kf0, qf0, st[0], 0, 0, 0);\
      st[1] = __builtin_amdgcn_mfma_f32_16x16x32_bf16(kf1, qf0, st[1], 0, 0, 0);\
      st[2] = __builtin_amdgcn_mfma_f32_16x16x32_bf16(kf2, qf0, st[2], 0, 0, 0);\
      st[3] = __builtin_amdgcn_mfma_f32_16x16x32_bf16(kf3, qf0, st[3], 0, 0, 0);\
      kf0 = *(const short8*)((const char*)KS + BUF * 8192 + aK1);              \
      kf1 = *(const short8*)((const char*)KS + BUF * 8192 + aK1 + 2048);       \
      kf2 = *(const short8*)((const char*)KS + BUF * 8192 + aK1 + 4096);       \
      kf3 = *(const short8*)((const char*)KS + BUF * 8192 + aK1 + 6144);       \
      st[0] = __builtin_amdgcn_mfma_f32_16x16x32_bf16(kf0, qf1, st[0], 0, 0, 0);\
      st[1] = __builtin_amdgcn_mfma_f32_16x16x32_bf16(kf1, qf1, st[1], 0, 0, 0);\
      st[2] = __builtin_amdgcn_mfma_f32_16x16x32_bf16(kf2, qf1, st[2], 0, 0, 0);\
      st[3] = __builtin_amdgcn_mfma_f32_16x16x32_bf16(kf3, qf1, st[3], 0, 0, 0);\
    }                                                                          \
    __builtin_amdgcn_s_setprio(0);                                             \
    if (kt == qb) {                                                            \
      _Pragma("unroll") for (int tt = 0; tt < 4; ++tt)                         \
        _Pragma("unroll") for (int r = 0; r < 4; ++r) {                        \
          int tg = kt * 64 + tt * 16 + l4 * 4 + r;                             \
          if (tg > qg) st[tt][r] = -1e30f;                                     \
        }                                                                      \
    }                                                                          \
    float mx0 = fmaxf(fmaxf(st[0][0], st[0][1]), fmaxf(st[0][2], st[0][3]));   \
    float mx1 = fmaxf(fmaxf(st[1][0], st[1][1]), fmaxf(st[1][2], st[1][3]));   \
    float mx2 = fmaxf(fmaxf(st[2][0], st[2][1]), fmaxf(st[2][2], st[2][3]));   \
    float mx3 = fmaxf(fmaxf(st[3][0], st[3][1]), fmaxf(st[3][2], st[3][3]));   \
    float mt = fmaxf(fmaxf(mx0, mx1), fmaxf(mx2, mx3));                        \
    mt = fmaxf(mt, __shfl_xor(mt, 16));                                        \
    mt = fmaxf(mt, __shfl_xor(mt, 32));                                        \
    bool defer = __all(mt - m_run <= 8.0f);                                    \
    float m_use = defer ? m_run : fmaxf(m_run, mt);                            \
    float alpha = defer ? 1.0f : exp2f(m_run - m_use);                         \
    float lsp[4];                                                              \
    _Pragma("unroll") for (int tt = 0; tt < 4; ++tt) {                         \
      float e0 = exp2f(st[tt][0] - m_use);                                     \
      float e1 = exp2f(st[tt][1] - m_use);                                     \
      float e2 = exp2f(st[tt][2] - m_use);                                     \
      float e3 = exp2f(st[tt][3] - m_use);                                     \
      st[tt][0] = e0; st[tt][1] = e1;                                          \
      lsp[tt] = (e0 + e1) + (e2 + e3);                                         \
      uint2 pk;                                                                \
      pk.x = cvtpk(e0, e1);                                                    \
      pk.y = cvtpk(e2, e3);                                                    \
      *(uint2*)((char*)Ps + (pwb ^ (tt << 5))) = pk;                           \
    }                                                                          \
    float lsum = (lsp[0] + lsp[1]) + (lsp[2] + lsp[3]);                        \
    lsum += __shfl_xor(lsum, 16);                                              \
    lsum += __shfl_xor(lsum, 32);                                              \
    l_run = l_run * alpha + lsum;                                              \
    m_run = m_use;                                                             \
    if (!defer) {                                                              \
      float a0 = __shfl(alpha, l4 * 4 + 0);                                    \
      float a1 = __shfl(alpha, l4 * 4 + 1);                                    \
      float a2 = __shfl(alpha, l4 * 4 + 2);                                    \
      float a3 = __shfl(alpha, l4 * 4 + 3);                                    \
      _Pragma("unroll") for (int dd = 0; dd < 4; ++dd) {                       \
        oA[dd][0] *= a0; oA[dd][1] *= a1; oA[dd][2] *= a2; oA[dd][3] *= a3;    \
      }                                                                        \
    }                                                                          \
    asm volatile("s_waitcnt lgkmcnt(0)" ::: "memory");                         \
    __builtin_amdgcn_s_setprio(1);                                             \
    {                                                                          \
      short8 pa = *(const short8*)((const char*)Ps + pr0);                     \
      short8 vb0 = *(const short8*)((const char*)VS + BUF * 8192 + aK0);       \
      short8 vb1 = *(const short8*)((const char*)VS + BUF * 8192 + aK0 + 2048);\
      short8 vb2 = *(const short8*)((const char*)VS + BUF * 8192 + aK0 + 4096);\
      short8 vb3 = *(const short8*)((const char*)VS + BUF * 8192 + aK0 + 6144);\
      oA[0] = __builtin_amdgcn_mfma_f32_16x16x32_bf16(pa, vb0, oA[0], 0, 0, 0);\
      oA[1] = __builtin_amdgcn_mfma_f32_16x16x32_bf16(pa, vb1, oA[1], 0, 0, 0);\
      oA[2] = __builtin_amdgcn_mfma_f32_16x16x32_bf16(pa, vb2, oA[2], 0, 0, 0);\
      oA[3] = __builtin_amdgcn_mfma_f32_16x16x32_bf16(pa, vb3, oA[3], 0, 0, 0);\
      pa = *(const short8*)((const char*)Ps + pr1);                            \
      vb0 = *(const short8*)((const char*)VS + BUF * 8192 + aK1);              \
      vb1 = *(const short8*)((const char*)VS + BUF * 8192 + aK1 + 2048);       \
      vb2 = *(const short8*)((const char*)VS + BUF * 8192 + aK1 + 4096);       \
      vb3 = *(const short8*)((const char*)VS + BUF * 8192 + aK1 + 6144);       \
      oA[0] = __builtin_amdgcn_mfma_f32_16x16x32_bf16(pa, vb0, oA[0], 0, 0, 0);\
      oA[1] = __builtin_amdgcn_mfma_f32_16x16x32_bf16(pa, vb1, oA[1], 0, 0, 0);\
      oA[2] = __builtin_amdgcn_mfma_f32_16x16x32_bf16(pa, vb2, oA[2], 0, 0, 0);\
      oA[3] = __builtin_amdgcn_mfma_f32_16x16x32_bf16(pa, vb3, oA[3], 0, 0, 0);\
    }                                                                          \
    __builtin_amdgcn_s_setprio(0);                                             \
  }

__global__ __launch_bounds__(256, 4) void attn_kernel(const u16* __restrict__ Qh,
                                                      const u16* __restrict__ Kh,
                                                      const u16* __restrict__ Vt,
                                                      u16* __restrict__ O) {
  __shared__ u16 KS[2][4096];   // 2 x 8KB K tile [64t][64d], XOR-swizzled rows
  __shared__ u16 VS[2][4096];   // 2 x 8KB V tile [64d][64t], XOR-swizzled rows
  __shared__ u16 Ps[4 * 1024];  // per-wave P tile [16 q][64 t]
  const int tid = threadIdx.x;
  const int lane = tid & 63;
  const int w = tid >> 6;
  const int blk = blockIdx.x;
  const int qb = 31 - (blk & 31);  // heavy blocks first (LPT)
  const int h = (blk >> 5) & 31;
  const int b = blk >> 10;
  const int kvh = h >> 2;
  const int qbase = qb * 64;
  const int l15 = lane & 15;
  const int l4 = lane >> 4;

  const u16* Qp = Qh + ((long)(b * NHEADS + h) * T_SEQ + qbase + w * 16 + l15) * HDIM;
  const short8 qf0 = *(const short8*)(Qp + l4 * 8);
  const short8 qf1 = *(const short8*)(Qp + 32 + l4 * 8);
  const u16* Kbase = Kh + (long)(b * KVHEADS + kvh) * T_SEQ * HDIM;
  const u16* Vbase = Vt + (long)(b * KVHEADS + kvh) * HDIM * T_SEQ;

  // LDS lane bases: read addr = base + compile-time offset (tt*2048, buf*8192)
  const int aK0 = l15 * 128 + ((l4 ^ (l15 & 7)) << 4);
  const int aK1 = l15 * 128 + (((4 + l4) ^ (l15 & 7)) << 4);
  const int pwb = w * 2048 + l15 * 128 + ((((l4 >> 1) ^ (l15 & 7))) << 4) + (l4 & 1) * 8;
  const int pr0 = w * 2048 + aK0;
  const int pr1 = w * 2048 + aK1;

  // staging lane offsets (2 granule-chunks per wave, K and V)
  int g0 = (w * 2 + 0) * 64 + lane, g1 = (w * 2 + 1) * 64 + lane;
  int r0 = g0 >> 3, s0g = (g0 & 7) ^ (r0 & 7);
  int r1 = g1 >> 3, s1g = (g1 & 7) ^ (r1 & 7);
  const int ld0 = g0 * 16, ld1 = g1 * 16;
  const u16* kg0 = Kbase + r0 * HDIM + s0g * 8;
  const u16* kg1 = Kbase + r1 * HDIM + s1g * 8;
  const u16* vg0 = Vbase + r0 * T_SEQ + s0g * 8;
  const u16* vg1 = Vbase + r1 * T_SEQ + s1g * 8;

  float m_run = -1e30f, l_run = 0.f;
  floatx4 oA[4] = {};
  const int qg = qbase + w * 16 + l15;  // this lane's q row (stats owner)

  // prologue: stage tile 0 into buf0; running ptrs advance to tile 1
  gld_lds16(kg0, (char*)KS + ld0);
  gld_lds16(kg1, (char*)KS + ld1);
  gld_lds16(vg0, (char*)VS + ld0);
  gld_lds16(vg1, (char*)VS + ld1);
  kg0 += 4096; kg1 += 4096; vg0 += 64; vg1 += 64;

  int kt = 0;
  for (;;) {
    ATT_BODY(0);
    if (kt >= qb) break;
    ++kt;
    ATT_BODY(1);
    if (kt >= qb) break;
    ++kt;
  }

  float linv = 1.0f / l_run;
  float i0 = __shfl(linv, l4 * 4 + 0);
  float i1 = __shfl(linv, l4 * 4 + 1);
  float i2 = __shfl(linv, l4 * 4 + 2);
  float i3 = __shfl(linv, l4 * 4 + 3);
  float iv[4] = {i0, i1, i2, i3};
#pragma unroll
  for (int dd = 0; dd < 4; ++dd)
#pragma unroll
    for (int r = 0; r < 4; ++r) {
      int trow = qbase + w * 16 + l4 * 4 + r;
      int col = h * 64 + dd * 16 + l15;
      O[((long)b * T_SEQ + trow) * DMODEL + col] = f2bf(oA[dd][r] * iv[r]);
    }
}

extern "C" void kernel_launch(void* const* d_in, const int* in_sizes, int n_in,
                              void* d_out, int out_size, void* d_ws, size_t ws_size,
                              hipStream_t stream) {
  const float* x = (const float*)d_in[0];
  const float* Wq = (const float*)d_in[1];
  const float* Wk = (const float*)d_in[2];
  const float* Wv = (const float*)d_in[3];
  const float* Wo = (const float*)d_in[4];
  float* out = (float*)d_out;

  // ws layout (bytes); Obuf aliases x_bf (dead after GEMM1). Total 88,604,672 B.
  char* ws = (char*)d_ws;
  u16* x_bf = (u16*)(ws);                    // 16,777,216
  u16* Obuf = (u16*)(ws);                    // alias
  u16* Wqkv_bf = (u16*)(ws + 16777216);      // 12,582,912
  u16* Wo_bf = (u16*)(ws + 29360128);        //  8,388,608
  u16* QKV = (u16*)(ws + 37748736);          // 25,165,824
  u16* Qh = (u16*)(ws + 62914560);           // 16,777,216
  u16* Kh = (u16*)(ws + 79691776);           //  4,194,304
  u16* Vt = (u16*)(ws + 83886080);           //  4,194,304
  float* cosT = (float*)(ws + 88080384);     //    262,144
  float* sinT = (float*)(ws + 88342528);     //    262,144

  // casts
  cvt_kernel<<<8192, 256, 0, stream>>>(x, x_bf, 2097152);
  cvt_kernel<<<4096, 256, 0, stream>>>(Wq, Wqkv_bf, 1048576);
  cvt_kernel<<<1024, 256, 0, stream>>>(Wk, Wqkv_bf + 2048 * 2048, 262144);
  cvt_kernel<<<1024, 256, 0, stream>>>(Wv, Wqkv_bf + 2560 * 2048, 262144);
  cvt_kernel<<<4096, 256, 0, stream>>>(Wo, Wo_bf, 1048576);
  rope_table_kernel<<<256, 256, 0, stream>>>(cosT, sinT);

  // QKV projection: [4096,2048] x [3072,2048]^T -> [4096,3072] bf16
  dim3 g1(24, 32);
  gemm_bt<false><<<g1, 256, 0, stream>>>(x_bf, Wqkv_bf, nullptr, QKV, 4096, 3072, 2048);

  rope_apply_kernel<<<40960, 256, 0, stream>>>(QKV, cosT, sinT, Qh, Kh);
  v_transpose_kernel<<<512, 256, 0, stream>>>(QKV, Vt);

  attn_kernel<<<2048, 256, 0, stream>>>(Qh, Kh, Vt, Obuf);

  // out projection: [4096,2048] x [2048,2048]^T -> f32 d_out
  dim3 g2(16, 32);
  gemm_bt<true><<<g2, 256, 0, stream>>>(Obuf, Wo_bf, out, nullptr, 4096, 2048, 2048);
}

// Round 9
// 369.061 us; speedup vs baseline: 1.5435x; 1.0069x over previous
//
#include <hip/hip_runtime.h>
#include <stdint.h>

// Pipeline: cast->bf16 | rope table | QKV GEMM (bf16 MFMA) | rope+layout |
//           V-transpose | flash attention (staged dbuf, 32q/wave) | out-proj
// B=2 T=2048 D_MODEL=2048 H=32 KVH=8 HD=64

typedef unsigned short u16;
typedef __attribute__((ext_vector_type(8))) short short8;
typedef __attribute__((ext_vector_type(4))) float floatx4;

#define T_SEQ 2048
#define DMODEL 2048
#define NHEADS 32
#define KVHEADS 8
#define HDIM 64
// 0.125 (1/sqrt(64)) * log2(e): QK^T then exp2 == exp(0.125*qk)
#define QK_SCALE 0.1803368801111204f

__device__ __forceinline__ u16 f2bf(float f) {
  uint32_t u = __builtin_bit_cast(uint32_t, f);
  u = (u + 0x7FFFu + ((u >> 16) & 1u)) >> 16;
  return (u16)u;
}
__device__ __forceinline__ float bf2f(u16 h) {
  uint32_t u = ((uint32_t)h) << 16;
  return __builtin_bit_cast(float, u);
}
__device__ __forceinline__ uint32_t cvtpk(float a, float b) {  // lo=a, hi=b
  uint32_t r;
  asm("v_cvt_pk_bf16_f32 %0, %1, %2" : "=v"(r) : "v"(a), "v"(b));
  return r;
}

__device__ __forceinline__ void gld_lds16(const void* g, void* l) {
  __builtin_amdgcn_global_load_lds(
      (const __attribute__((address_space(1))) unsigned int*)g,
      (__attribute__((address_space(3))) unsigned int*)l, 16, 0, 0);
}

// ---------------- f32 -> bf16 cast (x4 vectorized) ----------------
__global__ __launch_bounds__(256) void cvt_kernel(const float* __restrict__ src,
                                                  u16* __restrict__ dst, int n4) {
  int i = blockIdx.x * 256 + threadIdx.x;
  if (i >= n4) return;
  float4 v = ((const float4*)src)[i];
  ushort4 o;
  o.x = f2bf(v.x); o.y = f2bf(v.y); o.z = f2bf(v.z); o.w = f2bf(v.w);
  ((ushort4*)dst)[i] = o;
}

// ---------------- rope table: cos/sin [T][32] ----------------
__global__ __launch_bounds__(256) void rope_table_kernel(float* __restrict__ cosT,
                                                         float* __restrict__ sinT) {
  int idx = blockIdx.x * 256 + threadIdx.x;  // 65536 = 2048*32
  int t = idx >> 5, i = idx & 31;
  float invf = 1.0f / powf(10000.0f, (float)i / 32.0f);
  float a = (float)t * invf;
  cosT[idx] = cosf(a);
  sinT[idx] = sinf(a);
}

// ---------------- bf16 GEMM, A[M,K] * B[N,K]^T -> C[M,N] ----------------
template <bool OUT_F32>
__global__ __launch_bounds__(256) void gemm_bt(const u16* __restrict__ A,
                                               const u16* __restrict__ Bm,
                                               float* __restrict__ Cf,
                                               u16* __restrict__ Cb,
                                               int M, int N, int K) {
  __shared__ u16 As[128 * 64];
  __shared__ u16 Bs[128 * 64];
  const int tid = threadIdx.x;
  const int lane = tid & 63;
  const int wid = tid >> 6;
  const int wr = wid >> 1, wc = wid & 1;
  const long bm = (long)blockIdx.y * 128;
  const long bn = (long)blockIdx.x * 128;

  floatx4 acc[4][4] = {};

  for (int kt = 0; kt < K; kt += 64) {
#pragma unroll
    for (int c = 0; c < 4; ++c) {
      int g = (wid * 4 + c) * 64 + lane;      // 16B granule index, 1024 total
      int row = g >> 3, slot = g & 7;
      int ss = slot ^ (row & 7);              // inverse-swizzle the SOURCE
      gld_lds16(A + (bm + row) * (long)K + kt + ss * 8, (char*)As + g * 16);
      gld_lds16(Bm + (bn + row) * (long)K + kt + ss * 8, (char*)Bs + g * 16);
    }
    __syncthreads();
#pragma unroll
    for (int ks = 0; ks < 2; ++ks) {
      short8 af[4], bfr[4];
#pragma unroll
      for (int m = 0; m < 4; ++m) {
        int row = wr * 64 + m * 16 + (lane & 15);
        int slot = (ks * 4 + (lane >> 4)) ^ (row & 7);
        af[m] = *(const short8*)((const char*)As + row * 128 + slot * 16);
      }
#pragma unroll
      for (int n = 0; n < 4; ++n) {
        int row = wc * 64 + n * 16 + (lane & 15);
        int slot = (ks * 4 + (lane >> 4)) ^ (row & 7);
        bfr[n] = *(const short8*)((const char*)Bs + row * 128 + slot * 16);
      }
#pragma unroll
      for (int m = 0; m < 4; ++m)
#pragma unroll
        for (int n = 0; n < 4; ++n)
          acc[m][n] = __builtin_amdgcn_mfma_f32_16x16x32_bf16(af[m], bfr[n],
                                                              acc[m][n], 0, 0, 0);
    }
    __syncthreads();
  }
#pragma unroll
  for (int m = 0; m < 4; ++m)
#pragma unroll
    for (int n = 0; n < 4; ++n)
#pragma unroll
      for (int r = 0; r < 4; ++r) {
        long row = bm + wr * 64 + m * 16 + (lane >> 4) * 4 + r;
        long col = bn + wc * 64 + n * 16 + (lane & 15);
        if constexpr (OUT_F32)
          Cf[row * N + col] = acc[m][n][r];
        else
          Cb[row * N + col] = f2bf(acc[m][n][r]);
      }
}

// ---------------- RoPE + head layout for Q,K ----------------
// Q additionally pre-scaled by 0.125*log2(e) so attn softmax runs in exp2.
__global__ __launch_bounds__(256) void rope_apply_kernel(
    const u16* __restrict__ QKV, const float* __restrict__ cosT,
    const float* __restrict__ sinT, u16* __restrict__ Qh, u16* __restrict__ Kh) {
  int idx = blockIdx.x * 256 + threadIdx.x;  // B*T*2560
  int c = idx % 2560;
  int bt = idx / 2560;
  int t = bt & (T_SEQ - 1);
  int b = bt >> 11;
  int hd = c & 63;
  int i = hd & 31;
  float cs = cosT[t * 32 + i];
  float sn = sinT[t * 32 + i];
  long base = (long)bt * 3072;
  float xv = bf2f(QKV[base + c]);
  int pairc = (hd < 32) ? c + 32 : c - 32;
  float xp = bf2f(QKV[base + pairc]);
  float rot = (hd < 32) ? -xp : xp;
  float ov = xv * cs + rot * sn;
  if (c < 2048) {
    int h = c >> 6;
    Qh[((long)(b * NHEADS + h) * T_SEQ + t) * HDIM + hd] = f2bf(ov * QK_SCALE);
  } else {
    int kv = (c - 2048) >> 6;
    Kh[((long)(b * KVHEADS + kv) * T_SEQ + t) * HDIM + hd] = f2bf(ov);
  }
}

// ---------------- V transpose: QKV V-cols -> Vt[B][KVH][D][T] ----------------
__global__ __launch_bounds__(256) void v_transpose_kernel(const u16* __restrict__ QKV,
                                                          u16* __restrict__ Vt) {
  __shared__ u16 tl[64 * 65];
  int blk = blockIdx.x;  // 512 = B*KVH*(T/64)
  int ttile = blk & 31;
  int kvh = (blk >> 5) & 7;
  int b = blk >> 8;
  int tid = threadIdx.x;
  long bt0 = (long)b * T_SEQ + ttile * 64;
#pragma unroll
  for (int j = 0; j < 2; ++j) {
    int chunk = tid * 2 + j;
    int el = chunk * 8;
    int row = el >> 6, col = el & 63;
    short8 v = *(const short8*)(QKV + (bt0 + row) * 3072 + 2560 + kvh * 64 + col);
#pragma unroll
    for (int k = 0; k < 8; ++k) tl[(col + k) * 65 + row] = (u16)v[k];
  }
  __syncthreads();
#pragma unroll
  for (int j = 0; j < 2; ++j) {
    int chunk = tid * 2 + j;
    int el = chunk * 8;
    int d = el >> 6, t0 = el & 63;
    short8 o;
#pragma unroll
    for (int k = 0; k < 8; ++k) o[k] = (short)tl[d * 65 + t0 + k];
    *(short8*)(Vt + ((long)(b * KVHEADS + kvh) * HDIM + d) * T_SEQ + ttile * 64 + t0) = o;
  }
}

// ---------------- causal GQA flash attention ----------------
// 32 q-rows/wave (two 16-row frags A,B sharing K/V tile reads), 128 q/block.
// Staged dbuf, vmcnt+barrier at iter top, exp2 domain, shared running-max m
// across the lane's two rows (l per-row), defer-max, cvt_pk P-pack.
#define ATT_BODY(BUF)                                                          \
  {                                                                            \
    asm volatile("s_waitcnt vmcnt(0)" ::: "memory");                           \
    __builtin_amdgcn_s_barrier();                                              \
    asm volatile("" ::: "memory");                                             \
    if (kt < ktmax) {                                                          \
      gld_lds16(kg0, (char*)KS + ((BUF ^ 1) * 8192) + ld0);                    \
      gld_lds16(kg1, (char*)KS + ((BUF ^ 1) * 8192) + ld1);                    \
      gld_lds16(vg0, (char*)VS + ((BUF ^ 1) * 8192) + ld0);                    \
      gld_lds16(vg1, (char*)VS + ((BUF ^ 1) * 8192) + ld1);                    \
      kg0 += 4096; kg1 += 4096; vg0 += 64; vg1 += 64;                          \
    }                                                                          \
    floatx4 stA[4] = {}, stB[4] = {};                                          \
    __builtin_amdgcn_s_setprio(1);                                             \
    {                                                                          \
      short8 kf0 = *(const short8*)((const char*)KS + BUF * 8192 + aK0);       \
      short8 kf1 = *(const short8*)((const char*)KS + BUF * 8192 + aK0 + 2048);\
      short8 kf2 = *(const short8*)((const char*)KS + BUF * 8192 + aK0 + 4096);\
      short8 kf3 = *(const short8*)((const char*)KS + BUF * 8192 + aK0 + 6144);\
      stA[0] = __builtin_amdgcn_mfma_f32_16x16x32_bf16(kf0, qfA0, stA[0], 0, 0, 0);\
      stB[0] = __builtin_amdgcn_mfma_f32_16x16x32_bf16(kf0, qfB0, stB[0], 0, 0, 0);\
      stA[1] = __builtin_amdgcn_mfma_f32_16x16x32_bf16(kf1, qfA0, stA[1], 0, 0, 0);\
      stB[1] = __builtin_amdgcn_mfma_f32_16x16x32_bf16(kf1, qfB0, stB[1], 0, 0, 0);\
      stA[2] = __builtin_amdgcn_mfma_f32_16x16x32_bf16(kf2, qfA0, stA[2], 0, 0, 0);\
      stB[2] = __builtin_amdgcn_mfma_f32_16x16x32_bf16(kf2, qfB0, stB[2], 0, 0, 0);\
      stA[3] = __builtin_amdgcn_mfma_f32_16x16x32_bf16(kf3, qfA0, stA[3], 0, 0, 0);\
      stB[3] = __builtin_amdgcn_mfma_f32_16x16x32_bf16(kf3, qfB0, stB[3], 0, 0, 0);\
      kf0 = *(const short8*)((const char*)KS + BUF * 8192 + aK1);              \
      kf1 = *(const short8*)((const char*)KS + BUF * 8192 + aK1 + 2048);       \
      kf2 = *(const short8*)((const char*)KS + BUF * 8192 + aK1 + 4096);       \
      kf3 = *(const short8*)((const char*)KS + BUF * 8192 + aK1 + 6144);       \
      stA[0] = __builtin_amdgcn_mfma_f32_16x16x32_bf16(kf0, qfA1, stA[0], 0, 0, 0);\
      stB[0] = __builtin_amdgcn_mfma_f32_16x16x32_bf16(kf0, qfB1, stB[0], 0, 0, 0);\
      stA[1] = __builtin_amdgcn_mfma_f32_16x16x32_bf16(kf1, qfA1, stA[1], 0, 0, 0);\
      stB[1] = __builtin_amdgcn_mfma_f32_16x16x32_bf16(kf1, qfB1, stB[1], 0, 0, 0);\
      stA[2] = __builtin_amdgcn_mfma_f32_16x16x32_bf16(kf2, qfA1, stA[2], 0, 0, 0);\
      stB[2] = __builtin_amdgcn_mfma_f32_16x16x32_bf16(kf2, qfB1, stB[2], 0, 0, 0);\
      stA[3] = __builtin_amdgcn_mfma_f32_16x16x32_bf16(kf3, qfA1, stA[3], 0, 0, 0);\
      stB[3] = __builtin_amdgcn_mfma_f32_16x16x32_bf16(kf3, qfB1, stB[3], 0, 0, 0);\
    }                                                                          \
    __builtin_amdgcn_s_setprio(0);                                             \
    if (kt >= dt) {                                                            \
      _Pragma("unroll") for (int tt = 0; tt < 4; ++tt)                         \
        _Pragma("unroll") for (int r = 0; r < 4; ++r) {                        \
          int tg = kt * 64 + tt * 16 + l4 * 4 + r;                             \
          if (tg > qgA) stA[tt][r] = -1e30f;                                   \
          if (tg > qgB) stB[tt][r] = -1e30f;                                   \
        }                                                                      \
    }                                                                          \
    float mxA0 = fmaxf(fmaxf(stA[0][0], stA[0][1]), fmaxf(stA[0][2], stA[0][3]));\
    float mxA1 = fmaxf(fmaxf(stA[1][0], stA[1][1]), fmaxf(stA[1][2], stA[1][3]));\
    float mxA2 = fmaxf(fmaxf(stA[2][0], stA[2][1]), fmaxf(stA[2][2], stA[2][3]));\
    float mxA3 = fmaxf(fmaxf(stA[3][0], stA[3][1]), fmaxf(stA[3][2], stA[3][3]));\
    float mxB0 = fmaxf(fmaxf(stB[0][0], stB[0][1]), fmaxf(stB[0][2], stB[0][3]));\
    float mxB1 = fmaxf(fmaxf(stB[1][0], stB[1][1]), fmaxf(stB[1][2], stB[1][3]));\
    float mxB2 = fmaxf(fmaxf(stB[2][0], stB[2][1]), fmaxf(stB[2][2], stB[2][3]));\
    float mxB3 = fmaxf(fmaxf(stB[3][0], stB[3][1]), fmaxf(stB[3][2], stB[3][3]));\
    float mt = fmaxf(fmaxf(fmaxf(mxA0, mxA1), fmaxf(mxA2, mxA3)),              \
                     fmaxf(fmaxf(mxB0, mxB1), fmaxf(mxB2, mxB3)));             \
    mt = fmaxf(mt, __shfl_xor(mt, 16));                                        \
    mt = fmaxf(mt, __shfl_xor(mt, 32));                                        \
    bool defer = __all(mt - m_run <= 8.0f);                                    \
    float m_use = defer ? m_run : fmaxf(m_run, mt);                            \
    float alpha = defer ? 1.0f : exp2f(m_run - m_use);                         \
    float lsA = 0.f, lsB = 0.f;                                                \
    _Pragma("unroll") for (int tt = 0; tt < 4; ++tt) {                         \
      float e0 = exp2f(stA[tt][0] - m_use);                                    \
      float e1 = exp2f(stA[tt][1] - m_use);                                    \
      float e2 = exp2f(stA[tt][2] - m_use);                                    \
      float e3 = exp2f(stA[tt][3] - m_use);                                    \
      lsA += (e0 + e1) + (e2 + e3);                                            \
      uint2 pk;                                                                \
      pk.x = cvtpk(e0, e1);                                                    \
      pk.y = cvtpk(e2, e3);                                                    \
      *(uint2*)((char*)Ps + (pwbA ^ (tt << 5))) = pk;                          \
      float f0 = exp2f(stB[tt][0] - m_use);                                    \
      float f1 = exp2f(stB[tt][1] - m_use);                                    \
      float f2 = exp2f(stB[tt][2] - m_use);                                    \
      float f3 = exp2f(stB[tt][3] - m_use);                                    \
      lsB += (f0 + f1) + (f2 + f3);                                            \
      pk.x = cvtpk(f0, f1);                                                    \
      pk.y = cvtpk(f2, f3);                                                    \
      *(uint2*)((char*)Ps + (pwbB ^ (tt << 5))) = pk;                          \
    }                                                                          \
    lsA += __shfl_xor(lsA, 16);                                                \
    lsA += __shfl_xor(lsA, 32);                                                \
    lsB += __shfl_xor(lsB, 16);                                                \
    lsB += __shfl_xor(lsB, 32);                                                \
    l_runA = l_runA * alpha + lsA;                                             \
    l_runB = l_runB * alpha + lsB;                                             \
    m_run = m_use;                                                             \
    if (!defer) {                                                              \
      float a0 = __shfl(alpha, l4 * 4 + 0);                                    \
      float a1 = __shfl(alpha, l4 * 4 + 1);                                    \
      float a2 = __shfl(alpha, l4 * 4 + 2);                                    \
      float a3 = __shfl(alpha, l4 * 4 + 3);                                    \
      _Pragma("unroll") for (int dd = 0; dd < 4; ++dd) {                       \
        oA[dd][0] *= a0; oA[dd][1] *= a1; oA[dd][2] *= a2; oA[dd][3] *= a3;    \
        oB[dd][0] *= a0; oB[dd][1] *= a1; oB[dd][2] *= a2; oB[dd][3] *= a3;    \
      }                                                                        \
    }                                                                          \
    asm volatile("s_waitcnt lgkmcnt(0)" ::: "memory");                         \
    __builtin_amdgcn_s_setprio(1);                                             \
    {                                                                          \
      short8 paA = *(const short8*)((const char*)Ps + prA0);                   \
      short8 paB = *(const short8*)((const char*)Ps + prB0);                   \
      short8 vb0 = *(const short8*)((const char*)VS + BUF * 8192 + aK0);       \
      short8 vb1 = *(const short8*)((const char*)VS + BUF * 8192 + aK0 + 2048);\
      short8 vb2 = *(const short8*)((const char*)VS + BUF * 8192 + aK0 + 4096);\
      short8 vb3 = *(const short8*)((const char*)VS + BUF * 8192 + aK0 + 6144);\
      oA[0] = __builtin_amdgcn_mfma_f32_16x16x32_bf16(paA, vb0, oA[0], 0, 0, 0);\
      oB[0] = __builtin_amdgcn_mfma_f32_16x16x32_bf16(paB, vb0, oB[0], 0, 0, 0);\
      oA[1] = __builtin_amdgcn_mfma_f32_16x16x32_bf16(paA, vb1, oA[1], 0, 0, 0);\
      oB[1] = __builtin_amdgcn_mfma_f32_16x16x32_bf16(paB, vb1, oB[1], 0, 0, 0);\
      oA[2] = __builtin_amdgcn_mfma_f32_16x16x32_bf16(paA, vb2, oA[2], 0, 0, 0);\
      oB[2] = __builtin_amdgcn_mfma_f32_16x16x32_bf16(paB, vb2, oB[2], 0, 0, 0);\
      oA[3] = __builtin_amdgcn_mfma_f32_16x16x32_bf16(paA, vb3, oA[3], 0, 0, 0);\
      oB[3] = __builtin_amdgcn_mfma_f32_16x16x32_bf16(paB, vb3, oB[3], 0, 0, 0);\
      paA = *(const short8*)((const char*)Ps + prA1);                          \
      paB = *(const short8*)((const char*)Ps + prB1);                          \
      vb0 = *(const short8*)((const char*)VS + BUF * 8192 + aK1);              \
      vb1 = *(const short8*)((const char*)VS + BUF * 8192 + aK1 + 2048);       \
      vb2 = *(const short8*)((const char*)VS + BUF * 8192 + aK1 + 4096);       \
      vb3 = *(const short8*)((const char*)VS + BUF * 8192 + aK1 + 6144);       \
      oA[0] = __builtin_amdgcn_mfma_f32_16x16x32_bf16(paA, vb0, oA[0], 0, 0, 0);\
      oB[0] = __builtin_amdgcn_mfma_f32_16x16x32_bf16(paB, vb0, oB[0], 0, 0, 0);\
      oA[1] = __builtin_amdgcn_mfma_f32_16x16x32_bf16(paA, vb1, oA[1], 0, 0, 0);\
      oB[1] = __builtin_amdgcn_mfma_f32_16x16x32_bf16(paB, vb1, oB[1], 0, 0, 0);\
      oA[2] = __builtin_amdgcn_mfma_f32_16x16x32_bf16(paA, vb2, oA[2], 0, 0, 0);\
      oB[2] = __builtin_amdgcn_mfma_f32_16x16x32_bf16(paB, vb2, oB[2], 0, 0, 0);\
      oA[3] = __builtin_amdgcn_mfma_f32_16x16x32_bf16(paA, vb3, oA[3], 0, 0, 0);\
      oB[3] = __builtin_amdgcn_mfma_f32_16x16x32_bf16(paB, vb3, oB[3], 0, 0, 0);\
    }                                                                          \
    __builtin_amdgcn_s_setprio(0);                                             \
  }

__global__ __launch_bounds__(256, 3) void attn_kernel(const u16* __restrict__ Qh,
                                                      const u16* __restrict__ Kh,
                                                      const u16* __restrict__ Vt,
                                                      u16* __restrict__ O) {
  __shared__ u16 KS[2][4096];   // 2 x 8KB K tile [64t][64d], XOR-swizzled rows
  __shared__ u16 VS[2][4096];   // 2 x 8KB V tile [64d][64t], XOR-swizzled rows
  __shared__ u16 Ps[4 * 2048];  // per-wave P tiles: frag A + frag B (4KB/wave)
  const int tid = threadIdx.x;
  const int lane = tid & 63;
  const int w = tid >> 6;
  const int blk = blockIdx.x;
  const int qbi = 15 - (blk & 15);  // heavy blocks first (LPT)
  const int h = (blk >> 4) & 31;
  const int b = blk >> 9;
  const int kvh = h >> 2;
  const int qbase = qbi * 128;
  const int l15 = lane & 15;
  const int l4 = lane >> 4;
  const int ktmax = 2 * qbi + 1;
  const int dt = 2 * qbi + (w >> 1);  // wave's diagonal tile

  const u16* Qp = Qh + ((long)(b * NHEADS + h) * T_SEQ + qbase + w * 32 + l15) * HDIM;
  const short8 qfA0 = *(const short8*)(Qp + l4 * 8);
  const short8 qfA1 = *(const short8*)(Qp + 32 + l4 * 8);
  const short8 qfB0 = *(const short8*)(Qp + 16 * HDIM + l4 * 8);
  const short8 qfB1 = *(const short8*)(Qp + 16 * HDIM + 32 + l4 * 8);
  const u16* Kbase = Kh + (long)(b * KVHEADS + kvh) * T_SEQ * HDIM;
  const u16* Vbase = Vt + (long)(b * KVHEADS + kvh) * HDIM * T_SEQ;

  // LDS lane bases: read addr = base + compile-time offset (tt*2048, buf*8192)
  const int aK0 = l15 * 128 + ((l4 ^ (l15 & 7)) << 4);
  const int aK1 = l15 * 128 + (((4 + l4) ^ (l15 & 7)) << 4);
  const int pwbA = w * 4096 + l15 * 128 + ((((l4 >> 1) ^ (l15 & 7))) << 4) + (l4 & 1) * 8;
  const int pwbB = pwbA + 2048;
  const int prA0 = w * 4096 + aK0;
  const int prA1 = w * 4096 + aK1;
  const int prB0 = prA0 + 2048;
  const int prB1 = prA1 + 2048;

  // staging lane offsets (2 granule-chunks per wave, K and V)
  int g0 = (w * 2 + 0) * 64 + lane, g1 = (w * 2 + 1) * 64 + lane;
  int r0 = g0 >> 3, s0g = (g0 & 7) ^ (r0 & 7);
  int r1 = g1 >> 3, s1g = (g1 & 7) ^ (r1 & 7);
  const int ld0 = g0 * 16, ld1 = g1 * 16;
  const u16* kg0 = Kbase + r0 * HDIM + s0g * 8;
  const u16* kg1 = Kbase + r1 * HDIM + s1g * 8;
  const u16* vg0 = Vbase + r0 * T_SEQ + s0g * 8;
  const u16* vg1 = Vbase + r1 * T_SEQ + s1g * 8;

  float m_run = -1e30f, l_runA = 0.f, l_runB = 0.f;
  floatx4 oA[4] = {}, oB[4] = {};
  const int qgA = qbase + w * 32 + l15;  // frag A row owned by this lane
  const int qgB = qgA + 16;              // frag B row

  // prologue: stage tile 0 into buf0; running ptrs advance to tile 1
  gld_lds16(kg0, (char*)KS + ld0);
  gld_lds16(kg1, (char*)KS + ld1);
  gld_lds16(vg0, (char*)VS + ld0);
  gld_lds16(vg1, (char*)VS + ld1);
  kg0 += 4096; kg1 += 4096; vg0 += 64; vg1 += 64;

  int kt = 0;
  for (;;) {
    ATT_BODY(0);
    if (kt >= ktmax) break;
    ++kt;
    ATT_BODY(1);
    if (kt >= ktmax) break;
    ++kt;
  }

  float linvA = 1.0f / l_runA;
  float linvB = 1.0f / l_runB;
  float iA0 = __shfl(linvA, l4 * 4 + 0);
  float iA1 = __shfl(linvA, l4 * 4 + 1);
  float iA2 = __shfl(linvA, l4 * 4 + 2);
  float iA3 = __shfl(linvA, l4 * 4 + 3);
  float iB0 = __shfl(linvB, l4 * 4 + 0);
  float iB1 = __shfl(linvB, l4 * 4 + 1);
  float iB2 = __shfl(linvB, l4 * 4 + 2);
  float iB3 = __shfl(linvB, l4 * 4 + 3);
  float ivA[4] = {iA0, iA1, iA2, iA3};
  float ivB[4] = {iB0, iB1, iB2, iB3};
#pragma unroll
  for (int dd = 0; dd < 4; ++dd)
#pragma unroll
    for (int r = 0; r < 4; ++r) {
      int trowA = qbase + w * 32 + l4 * 4 + r;
      int col = h * 64 + dd * 16 + l15;
      O[((long)b * T_SEQ + trowA) * DMODEL + col] = f2bf(oA[dd][r] * ivA[r]);
      O[((long)b * T_SEQ + trowA + 16) * DMODEL + col] = f2bf(oB[dd][r] * ivB[r]);
    }
}

extern "C" void kernel_launch(void* const* d_in, const int* in_sizes, int n_in,
                              void* d_out, int out_size, void* d_ws, size_t ws_size,
                              hipStream_t stream) {
  const float* x = (const float*)d_in[0];
  const float* Wq = (const float*)d_in[1];
  const float* Wk = (const float*)d_in[2];
  const float* Wv = (const float*)d_in[3];
  const float* Wo = (const float*)d_in[4];
  float* out = (float*)d_out;

  // ws layout (bytes); Obuf aliases x_bf (dead after GEMM1). Total 88,604,672 B.
  char* ws = (char*)d_ws;
  u16* x_bf = (u16*)(ws);                    // 16,777,216
  u16* Obuf = (u16*)(ws);                    // alias
  u16* Wqkv_bf = (u16*)(ws + 16777216);      // 12,582,912
  u16* Wo_bf = (u16*)(ws + 29360128);        //  8,388,608
  u16* QKV = (u16*)(ws + 37748736);          // 25,165,824
  u16* Qh = (u16*)(ws + 62914560);           // 16,777,216
  u16* Kh = (u16*)(ws + 79691776);           //  4,194,304
  u16* Vt = (u16*)(ws + 83886080);           //  4,194,304
  float* cosT = (float*)(ws + 88080384);     //    262,144
  float* sinT = (float*)(ws + 88342528);     //    262,144

  // casts
  cvt_kernel<<<8192, 256, 0, stream>>>(x, x_bf, 2097152);
  cvt_kernel<<<4096, 256, 0, stream>>>(Wq, Wqkv_bf, 1048576);
  cvt_kernel<<<1024, 256, 0, stream>>>(Wk, Wqkv_bf + 2048 * 2048, 262144);
  cvt_kernel<<<1024, 256, 0, stream>>>(Wv, Wqkv_bf + 2560 * 2048, 262144);
  cvt_kernel<<<4096, 256, 0, stream>>>(Wo, Wo_bf, 1048576);
  rope_table_kernel<<<256, 256, 0, stream>>>(cosT, sinT);

  // QKV projection: [4096,2048] x [3072,2048]^T -> [4096,3072] bf16
  dim3 g1(24, 32);
  gemm_bt<false><<<g1, 256, 0, stream>>>(x_bf, Wqkv_bf, nullptr, QKV, 4096, 3072, 2048);

  rope_apply_kernel<<<40960, 256, 0, stream>>>(QKV, cosT, sinT, Qh, Kh);
  v_transpose_kernel<<<512, 256, 0, stream>>>(QKV, Vt);

  attn_kernel<<<1024, 256, 0, stream>>>(Qh, Kh, Vt, Obuf);

  // out projection: [4096,2048] x [2048,2048]^T -> f32 d_out
  dim3 g2(16, 32);
  gemm_bt<true><<<g2, 256, 0, stream>>>(Obuf, Wo_bf, out, nullptr, 4096, 2048, 2048);
}